// Round 9
// baseline (224.713 us; speedup 1.0000x reference)
//
#include <hip/hip_runtime.h>

// Bidirectional GRU (H=32, input=1, B=2048, T=512) + MLP head, fully fused.
//
// Reference takes out[:, -1, :] = concat(h_fwd after T steps, h_bwd after ONE
// step from h0=0 on x[T-1]) -> only the forward scan is sequential; W_hh_b is
// entirely unused.
//
// R9 = K-split-2 over f16 dot2, 2 waves/SIMD.
//
// R8 post-mortem: 113.5 us = 532 cyc/step = 325 issue (VALUBusy 61%) + ~207
// exposed stall (LDS RT ~130 + trans tail ~80) at 1 wave/SIMD.  Fix both:
// split K across the two wave halves (lane (i, k=L>>5) computes the 16-wide
// k-half of the r/z/n dots for output i; full dots via one shfl_xor(32) per
// gate).  Per-wave issue halves (~120 cyc); 2048 waves = 2 waves/SIMD so the
// other wave issues during this wave's LDS/trans stalls.  R3 tried this
// shape and lost, but R3's poison was fp32 weight spills + spill-starved
// serialization -- with f16 weights the whole wave state is ~75 VGPRs under
// a 256-reg budget (amdgpu_waves_per_eu(2,2)): zero spill pressure.
//
//   * Weights f16 packed (8 h2 per gate = 24 VGPRs), pre-scaled into exp2
//     domain (r/z by -log2e, n by 2log2e), pinned via inline-asm.
//   * h state fp32 per lane; broadcast copy f16: lane (i,k) writes
//     hbuf[w][k][i] (ds_write_b16, 2-way bank pairing = free), half k reads
//     its 16 h as 2 broadcast ds_read_b128.
//   * x staged in LDS f32, consumed as vf4 per 4 steps (prefetched).
//   * sigmoid = v_rcp(1+v_exp2(.)), tanh = 1-2*v_rcp(1+v_exp2(.)).
//   * Grid: 512 blocks x 256 thr = 2048 waves (1 row/wave) = 2 waves/SIMD.

typedef float vf2 __attribute__((ext_vector_type(2)));
typedef float vf4 __attribute__((ext_vector_type(4)));
typedef _Float16 f16;
typedef f16 h2 __attribute__((ext_vector_type(2)));
typedef f16 h8 __attribute__((ext_vector_type(8)));

#define TT 512
#define HH 32

// inline-asm defs are not rematerializable: forces a real VGPR def here.
#define PIN(v) asm volatile("" : "+v"(v))

#define LOG2E 1.44269504f

__device__ __forceinline__ float fast_sigm(float a) {   // sigmoid(a)
  return __builtin_amdgcn_rcpf(1.0f + __builtin_amdgcn_exp2f(-LOG2E * a));
}
__device__ __forceinline__ float fast_tanh(float a) {   // tanh(a)
  return __builtin_fmaf(-2.0f,
      __builtin_amdgcn_rcpf(1.0f + __builtin_amdgcn_exp2f(2.0f * LOG2E * a)),
      1.0f);
}

__device__ __forceinline__ h2 pack_h2(vf2 a, float s) {
  h2 r = {(f16)(a.x * s), (f16)(a.y * s)};
  return r;
}

// load this lane's 16-wide k-half of one W_hh row as 8 packed-f16 h2, pinned
#define LDW8(P, BASE, S) \
  h2 P##0=pack_h2(Wp[(BASE)+0],(S)), P##1=pack_h2(Wp[(BASE)+1],(S)), \
     P##2=pack_h2(Wp[(BASE)+2],(S)), P##3=pack_h2(Wp[(BASE)+3],(S)), \
     P##4=pack_h2(Wp[(BASE)+4],(S)), P##5=pack_h2(Wp[(BASE)+5],(S)), \
     P##6=pack_h2(Wp[(BASE)+6],(S)), P##7=pack_h2(Wp[(BASE)+7],(S)); \
  PIN(P##0);PIN(P##1);PIN(P##2);PIN(P##3);PIN(P##4);PIN(P##5);PIN(P##6);PIN(P##7)

// 8 v_dot2_f32_f16 of (q0..q7).(P0..P7) -> two chains of 4, summed to float
#define FDOT8(RES, P) \
  float RES; \
  { float c0 = __builtin_amdgcn_fdot2(q0, P##0, 0.0f, false); \
    float c1 = __builtin_amdgcn_fdot2(q1, P##1, 0.0f, false); \
    c0 = __builtin_amdgcn_fdot2(q2, P##2, c0, false); \
    c1 = __builtin_amdgcn_fdot2(q3, P##3, c1, false); \
    c0 = __builtin_amdgcn_fdot2(q4, P##4, c0, false); \
    c1 = __builtin_amdgcn_fdot2(q5, P##5, c1, false); \
    c0 = __builtin_amdgcn_fdot2(q6, P##6, c0, false); \
    c1 = __builtin_amdgcn_fdot2(q7, P##7, c1, false); \
    RES = c0 + c1; }

__global__ __launch_bounds__(256)
__attribute__((amdgpu_waves_per_eu(2, 2)))
void gru_bidir_head(const float* __restrict__ X,
                    const float* __restrict__ Wih_f, const float* __restrict__ Whh_f,
                    const float* __restrict__ bih_f, const float* __restrict__ bhh_f,
                    const float* __restrict__ Wih_b,
                    const float* __restrict__ bih_b, const float* __restrict__ bhh_b,
                    const float* __restrict__ W1, const float* __restrict__ b1,
                    const float* __restrict__ W2, const float* __restrict__ b2,
                    float* __restrict__ out)
{
  __shared__ float xbuf[4][TT];        // staged input rows (8 KB)
  __shared__ f16   hbuf[4][2][HH];     // [row][K-half copy][i], f16 (512 B)
  __shared__ float obuf[4][64];        // [row][h_f(32) | h_b(32)] (1 KB)

  const int L = threadIdx.x & 63;      // lane in wave
  const int w = threadIdx.x >> 6;      // wave in block = row slot (0..3)
  const int i = L & 31;                // output element owned by this lane
  const int k = L >> 5;                // K-half: h[16k .. 16k+16)
  const int b = (blockIdx.x << 2) + w; // global batch row

  // --- stage this wave's X row into LDS (2 x vf4 per lane, coalesced) ---
  const vf4* Xr4 = (const vf4*)(X + (size_t)b * TT);
  vf4* xb4 = (vf4*)&xbuf[w][0];
  xb4[L]      = Xr4[L];
  xb4[64 + L] = Xr4[64 + L];

  // --- per-lane weights: rows {i, 32+i, 64+i}, cols [16k, 16k+16);
  //     pre-scaled into exp2 domain, packed f16, pinned (24 VGPRs) ---
  const vf2* Wp = (const vf2*)Whh_f;   // row stride = 16 vf2
  const float s1 = -LOG2E;             // r,z: sigmoid domain (negated)
  const float s2 = 2.0f * LOG2E;       // n: tanh domain
  const int hb8 = k * 8;               // vf2 offset of this k-half
  LDW8(Wr, (i)        * 16 + hb8, s1);
  LDW8(Wz, (HH + i)   * 16 + hb8, s1);
  LDW8(Wn, (2*HH + i) * 16 + hb8, s2);

  float xwr = Wih_f[i] * s1, xwz = Wih_f[HH + i] * s1, xwn = Wih_f[2*HH + i] * s2;
  float cbr = (bih_f[i]      + bhh_f[i])      * s1;
  float cbz = (bih_f[HH + i] + bhh_f[HH + i]) * s1;
  float cbn = bih_f[2*HH + i] * s2;            // n: b_ih term (with x)
  float cbh = bhh_f[2*HH + i] * s2;            // n: b_hh term (inside r*(...))
  PIN(xwr); PIN(xwz); PIN(xwn); PIN(cbr); PIN(cbz); PIN(cbn); PIN(cbh);

  float h = 0.0f;
  hbuf[w][k][i] = (f16)0.0f;           // each copy fully zeroed by its half
  __builtin_amdgcn_wave_barrier();

  // this half's 16 h values from its own copy: 2 broadcast ds_read_b128
  const h8*  hv = (const h8*)&hbuf[w][k][16 * k];
  const vf4* xv = (const vf4*)&xbuf[w][0];
  vf4 x4 = xv[0];

  #pragma unroll 1
  for (int tg = 0; tg < TT / 4; ++tg) {
    const vf4 x4n = xv[tg + 1 < TT / 4 ? tg + 1 : tg];   // off critical path
    #pragma unroll
    for (int u = 0; u < 4; ++u) {
      const float x = (u == 0) ? x4.x : (u == 1) ? x4.y : (u == 2) ? x4.z : x4.w;

      h8 H0 = hv[0], H1 = hv[1];
      h2 q0 = {H0[0], H0[1]}, q1 = {H0[2], H0[3]},
         q2 = {H0[4], H0[5]}, q3 = {H0[6], H0[7]},
         q4 = {H1[0], H1[1]}, q5 = {H1[2], H1[3]},
         q6 = {H1[4], H1[5]}, q7 = {H1[6], H1[7]};
      asm volatile("" : "+v"(q0), "+v"(q1), "+v"(q2), "+v"(q3),
                        "+v"(q4), "+v"(q5), "+v"(q6), "+v"(q7));

      FDOT8(pr, Wr);                   // partial dots over this k-half
      FDOT8(pz, Wz);
      FDOT8(pn, Wn);
      pr += __shfl_xor(pr, 32, 64);    // combine K-halves (3 indep shfls)
      pz += __shfl_xor(pz, 32, 64);
      pn += __shfl_xor(pn, 32, 64);

      const float ar = __builtin_fmaf(x, xwr, cbr) + pr;
      const float az = __builtin_fmaf(x, xwz, cbz) + pz;
      const float r = __builtin_amdgcn_rcpf(1.0f + __builtin_amdgcn_exp2f(ar));
      const float z = __builtin_amdgcn_rcpf(1.0f + __builtin_amdgcn_exp2f(az));
      const float y = __builtin_fmaf(r, pn + cbh, __builtin_fmaf(x, xwn, cbn));
      const float n = __builtin_fmaf(-2.0f,
          __builtin_amdgcn_rcpf(1.0f + __builtin_amdgcn_exp2f(y)), 1.0f);
      h = __builtin_fmaf(z, h - n, n);           // (1-z)*n + z*h

      hbuf[w][k][i] = (f16)h;                    // refresh this half's copy
      __builtin_amdgcn_wave_barrier();           // wave-synchronous ordering
    }
    x4 = x4n;
  }

  // --- backward direction: exactly ONE GRU step from h0=0 on x[T-1] ---
  const float xl  = xbuf[w][TT - 1];
  const float rb  = fast_sigm(__builtin_fmaf(xl, Wih_b[i],      bih_b[i]      + bhh_b[i]));
  const float zb  = fast_sigm(__builtin_fmaf(xl, Wih_b[HH + i], bih_b[HH + i] + bhh_b[HH + i]));
  const float xnb = __builtin_fmaf(xl, Wih_b[2*HH + i], bih_b[2*HH + i]);
  const float nb  = fast_tanh(__builtin_fmaf(rb, bhh_b[2*HH + i], xnb));
  const float hb  = nb - zb * nb;                // (1-zb)*nb + zb*0

  // half 0 stores h_f, half 1 stores h_b -> obuf[w] = [h_f(32) | h_b(32)]
  obuf[w][k * 32 + i] = k ? hb : h;
  __builtin_amdgcn_wave_barrier();

  // --- MLP head: sigmoid(W2 @ relu(W1 @ [h_f,h_b] + b1) + b2) ---
  const int j = L & 15;                          // lanes 16..63 duplicate
  const vf4* W1r = (const vf4*)(W1 + j * 64);
  const vf4* hc  = (const vf4*)&obuf[w][0];
  vf4 a4 = W1r[0] * hc[0];
  #pragma unroll
  for (int q = 1; q < 16; ++q)
    a4 = __builtin_elementwise_fma(W1r[q], hc[q], a4);
  float acc = b1[j] + (a4.x + a4.y) + (a4.z + a4.w);
  float h1 = fmaxf(acc, 0.0f) * W2[j];
  h1 += __shfl_down(h1, 8, 16);
  h1 += __shfl_down(h1, 4, 16);
  h1 += __shfl_down(h1, 2, 16);
  h1 += __shfl_down(h1, 1, 16);
  if (L == 0) out[b] = fast_sigm(h1 + b2[0]);
}

extern "C" void kernel_launch(void* const* d_in, const int* in_sizes, int n_in,
                              void* d_out, int out_size, void* d_ws, size_t ws_size,
                              hipStream_t stream) {
  const float* X     = (const float*)d_in[0];
  const float* Wih_f = (const float*)d_in[1];
  const float* Whh_f = (const float*)d_in[2];
  const float* bih_f = (const float*)d_in[3];
  const float* bhh_f = (const float*)d_in[4];
  const float* Wih_b = (const float*)d_in[5];
  // d_in[6] = W_hh_b: unused — backward direction runs exactly one step from h0=0.
  const float* bih_b = (const float*)d_in[7];
  const float* bhh_b = (const float*)d_in[8];
  const float* W1    = (const float*)d_in[9];
  const float* b1    = (const float*)d_in[10];
  const float* W2    = (const float*)d_in[11];
  const float* b2    = (const float*)d_in[12];
  float* out = (float*)d_out;

  // 2048 rows, 1 row per wave (64 lanes, K-split-2), 4 waves per block
  // -> 512 blocks = 2 blocks/CU = 2 waves/SIMD.
  gru_bidir_head<<<512, 256, 0, stream>>>(X, Wih_f, Whh_f, bih_f, bhh_f,
                                          Wih_b, bih_b, bhh_b, W1, b1, W2, b2, out);
}